// Round 11
// baseline (253.290 us; speedup 1.0000x reference)
//
#include <hip/hip_runtime.h>
#include <math.h>

// Sizes (hard-coded per reference): B=1, L=256, D=128, H=4, DH=32
// positions P = L*L = 65536; HD = H*DH = 128
#define NPOS 65536

typedef _Float16 f16x8 __attribute__((ext_vector_type(8)));
typedef _Float16 f16x4 __attribute__((ext_vector_type(4)));
typedef float    f32x4 __attribute__((ext_vector_type(4)));

__device__ __forceinline__ unsigned short f16bits(_Float16 h) {
    return __builtin_bit_cast(unsigned short, h);
}

// ---------------------------------------------------------------------------
// Kernel P: transpose W{q,k,v,g} (fp32 [k=128][n=128]) into f16 hi plane only:
// Wt_hi[n_global=512][k=128]. Also emits WoT_hi[n=128][k=128] for the MFMA
// out_proj. Grid 320 blocks.
// ---------------------------------------------------------------------------
__global__ __launch_bounds__(256) void split_w_kernel(
    const float* __restrict__ Wq, const float* __restrict__ Wk,
    const float* __restrict__ Wv, const float* __restrict__ Wg,
    const float* __restrict__ Wo,
    _Float16* __restrict__ Wt_hi, _Float16* __restrict__ WoT_hi)
{
    int t = blockIdx.x * 256 + threadIdx.x;       // 0..81919
    if (t < 65536) {
        int ng = t >> 7, kk = t & 127;
        int mat = ng >> 7, n = ng & 127;
        const float* W = (mat == 0) ? Wq : (mat == 1) ? Wk : (mat == 2) ? Wv : Wg;
        Wt_hi[t] = (_Float16)W[kk * 128 + n];
    } else {
        int tt = t - 65536;                       // 0..16383
        int n = tt >> 7, kk = tt & 127;
        WoT_hi[tt] = (_Float16)Wo[kk * 128 + n];
    }
}

// ---------------------------------------------------------------------------
// Kernel A (round-7): LN + split-f16(A-side only) MFMA GEMM.  (unchanged)
// ---------------------------------------------------------------------------
__global__ __launch_bounds__(256, 4) void ln_proj_kernel(
    const float* __restrict__ pair, const float* __restrict__ ln_w, const float* __restrict__ ln_b,
    const float* __restrict__ Wb, const float* __restrict__ bg,
    const _Float16* __restrict__ Wt_hi,
    _Float16* __restrict__ q_hi, _Float16* __restrict__ q_lo,
    _Float16* __restrict__ k16, _Float16* __restrict__ v16, _Float16* __restrict__ g16,
    float* __restrict__ bias_n)
{
    __shared__ _Float16 xbuf[2][64][136];   // [0]: xh then Bh; [1]: xl then stg(u32[64][68])
    _Float16 (*xh)[136] = xbuf[0];
    _Float16 (*xl)[136] = xbuf[1];

    const int tid = threadIdx.x;
    const int p0  = blockIdx.x * 64;
    const int r   = tid >> 2;          // row 0..63
    const int cb  = (tid & 3) * 32;    // col base (4 threads/row)

    // ---- load 32 pair values (float4) ----
    float xv[32];
    {
        const float4* pr = (const float4*)(pair + (size_t)(p0 + r) * 128 + cb);
        #pragma unroll
        for (int i = 0; i < 8; ++i) {
            float4 t = pr[i];
            xv[i * 4 + 0] = t.x; xv[i * 4 + 1] = t.y;
            xv[i * 4 + 2] = t.z; xv[i * 4 + 3] = t.w;
        }
    }
    // ---- LN stats across the 4 threads of the row ----
    float sum = 0.f, sq = 0.f;
    #pragma unroll
    for (int i = 0; i < 32; ++i) { sum += xv[i]; sq += xv[i] * xv[i]; }
    sum += __shfl_xor(sum, 1); sq += __shfl_xor(sq, 1);
    sum += __shfl_xor(sum, 2); sq += __shfl_xor(sq, 2);
    float mean = sum * (1.f / 128.f);
    float var  = sq * (1.f / 128.f) - mean * mean;
    float rstd = rsqrtf(var + 1e-5f);

    // ---- normalize, split to f16 hi/lo, store to LDS; bias partial dots ----
    float b0 = 0.f, b1 = 0.f, b2 = 0.f, b3 = 0.f;
    #pragma unroll
    for (int i8 = 0; i8 < 4; ++i8) {
        float4 lw0 = *(const float4*)(ln_w + cb + i8 * 8);
        float4 lw1 = *(const float4*)(ln_w + cb + i8 * 8 + 4);
        float4 lb0 = *(const float4*)(ln_b + cb + i8 * 8);
        float4 lb1 = *(const float4*)(ln_b + cb + i8 * 8 + 4);
        float lw[8] = {lw0.x, lw0.y, lw0.z, lw0.w, lw1.x, lw1.y, lw1.z, lw1.w};
        float lb[8] = {lb0.x, lb0.y, lb0.z, lb0.w, lb1.x, lb1.y, lb1.z, lb1.w};
        f16x8 hv, lv;
        #pragma unroll
        for (int j = 0; j < 8; ++j) {
            int i = i8 * 8 + j;
            float xn = (xv[i] - mean) * rstd * lw[j] + lb[j];
            _Float16 h = (_Float16)xn;
            hv[j] = h;
            lv[j] = (_Float16)((xn - (float)h) * 2048.0f);
            float4 wb = *(const float4*)(Wb + (size_t)(cb + i) * 4);
            b0 = fmaf(xn, wb.x, b0); b1 = fmaf(xn, wb.y, b1);
            b2 = fmaf(xn, wb.z, b2); b3 = fmaf(xn, wb.w, b3);
        }
        *(f16x8*)&xh[r][cb + i8 * 8] = hv;
        *(f16x8*)&xl[r][cb + i8 * 8] = lv;
    }
    // reduce bias dots across the 4 threads of the row, store natural layout
    b0 += __shfl_xor(b0, 1); b1 += __shfl_xor(b1, 1);
    b2 += __shfl_xor(b2, 1); b3 += __shfl_xor(b3, 1);
    b0 += __shfl_xor(b0, 2); b1 += __shfl_xor(b1, 2);
    b2 += __shfl_xor(b2, 2); b3 += __shfl_xor(b3, 2);
    if ((tid & 3) == 0) {
        int p = p0 + r;                        // p = j*256 + kpos
        bias_n[0 * NPOS + p] = b0;
        bias_n[1 * NPOS + p] = b1;
        bias_n[2 * NPOS + p] = b2;
        bias_n[3 * NPOS + p] = b3;
    }
    __syncthreads();

    // ---- A fragments -> registers (16 rows per wave, full K=128) ----
    const int w  = tid >> 6, l = tid & 63;
    const int lm = l & 15, lg = l >> 4;
    const int arow = w * 16 + lm;

    f16x8 ahf[4], alf[4];
    #pragma unroll
    for (int kt = 0; kt < 4; ++kt) {
        ahf[kt] = *(const f16x8*)&xh[arow][kt * 32 + lg * 8];
        alf[kt] = *(const f16x8*)&xl[arow][kt * 32 + lg * 8];
    }

    _Float16 (*Bh)[136] = xbuf[0];                 // B chunk (single plane)
    unsigned* stg = (unsigned*)&xbuf[1][0][0];     // u32 [64][68] (hi | lo<<16)

    const float scale = 0.17677669529663687f;      // 1/sqrt(32)

    for (int chunk = 0; chunk < 8; ++chunk) {
        __syncthreads();   // stg(chunk-1) writes visible; Bh frag-reads done

        // issue B-chunk global loads (4 x 16B per thread)
        const _Float16* srch = Wt_hi + (size_t)(chunk * 64) * 128;
        f16x8 breg[4];
        #pragma unroll
        for (int it = 0; it < 4; ++it) {
            int idx = it * 256 + tid;
            breg[it] = *(const f16x8*)(srch + (idx >> 4) * 128 + (idx & 15) * 8);
        }

        // store previous chunk's outputs from stg (overlaps B-load latency)
        if (chunk > 0) {
            const int pm = (chunk - 1) >> 1, pcol = ((chunk - 1) & 1) * 64;
            #pragma unroll
            for (int it = 0; it < 4; ++it) {
                int idx = it * 256 + tid;
                int row = idx >> 4, c4 = (idx & 15) * 4;
                uint4 pk = *(const uint4*)&stg[row * 68 + c4];
                ushort4 hv = make_ushort4((unsigned short)(pk.x & 0xffff),
                                          (unsigned short)(pk.y & 0xffff),
                                          (unsigned short)(pk.z & 0xffff),
                                          (unsigned short)(pk.w & 0xffff));
                size_t off = (size_t)(p0 + row) * 128 + pcol + c4;
                if (pm == 0) {
                    *(ushort4*)(q_hi + off) = hv;
                    ushort4 lv = make_ushort4((unsigned short)(pk.x >> 16),
                                              (unsigned short)(pk.y >> 16),
                                              (unsigned short)(pk.z >> 16),
                                              (unsigned short)(pk.w >> 16));
                    *(ushort4*)(q_lo + off) = lv;
                } else if (pm == 1) *(ushort4*)(k16 + off) = hv;
                else if   (pm == 2) *(ushort4*)(v16 + off) = hv;
                else                *(ushort4*)(g16 + off) = hv;
            }
        }

        // write B chunk to LDS
        #pragma unroll
        for (int it = 0; it < 4; ++it) {
            int idx = it * 256 + tid;
            *(f16x8*)&Bh[idx >> 4][(idx & 15) * 8] = breg[it];
        }
        __syncthreads();   // B ready; stg free for rewrite

        // ---- MFMA: 4 col-tiles x 4 kt x 2 (x-split only) ----
        const int mat = chunk >> 1;
        f32x4 acch[4], accc[4];
        #pragma unroll
        for (int ct = 0; ct < 4; ++ct) {
            acch[ct] = (f32x4){0.f, 0.f, 0.f, 0.f};
            accc[ct] = (f32x4){0.f, 0.f, 0.f, 0.f};
        }
        #pragma unroll
        for (int kt = 0; kt < 4; ++kt) {
            const int koff = kt * 32 + lg * 8;
            #pragma unroll
            for (int ct = 0; ct < 4; ++ct) {
                f16x8 bh = *(const f16x8*)&Bh[ct * 16 + lm][koff];
                acch[ct] = __builtin_amdgcn_mfma_f32_16x16x32_f16(ahf[kt], bh, acch[ct], 0, 0, 0);
                accc[ct] = __builtin_amdgcn_mfma_f32_16x16x32_f16(alf[kt], bh, accc[ct], 0, 0, 0);
            }
        }

        // ---- epilogue math -> stg (packed u32) ----
        const int colhalf = (chunk & 1) * 64;
        #pragma unroll
        for (int ct = 0; ct < 4; ++ct) {
            const int col = ct * 16 + lm;
            float bgv = (mat == 3) ? bg[colhalf + col] : 0.f;
            #pragma unroll
            for (int rr = 0; rr < 4; ++rr) {
                float val = acch[ct][rr] + accc[ct][rr] * (1.0f / 2048.0f);
                if (mat == 0) val *= scale;
                if (mat == 3) val = 1.f / (1.f + __expf(-(val + bgv)));
                _Float16 h = (_Float16)val;
                unsigned pk = f16bits(h);
                if (mat == 0) {
                    _Float16 lo = (_Float16)((val - (float)h) * 2048.0f);
                    pk |= ((unsigned)f16bits(lo)) << 16;
                }
                stg[(w * 16 + lg * 4 + rr) * 68 + col] = pk;
            }
        }
    }

    // ---- final chunk store ----
    __syncthreads();
    {
        #pragma unroll
        for (int it = 0; it < 4; ++it) {
            int idx = it * 256 + tid;
            int row = idx >> 4, c4 = (idx & 15) * 4;
            uint4 pk = *(const uint4*)&stg[row * 68 + c4];
            ushort4 hv = make_ushort4((unsigned short)(pk.x & 0xffff),
                                      (unsigned short)(pk.y & 0xffff),
                                      (unsigned short)(pk.z & 0xffff),
                                      (unsigned short)(pk.w & 0xffff));
            *(ushort4*)(g16 + (size_t)(p0 + row) * 128 + 64 + c4) = hv;
        }
    }
}

// ---------------------------------------------------------------------------
// Kernel B (round-18): round-17 structure (proven new best: attn 77us,
// FETCH 90MB / WRITE 50MB near-ideal, total 230.2us) + sum-tree.
// Round-10 post-mortem: tree-max won -18us AND cut FETCH/WRITE by
// ~16/22MB — round-5's baseline had a ~20MB residual scratch spill that
// the shorter max chain's register profile eliminated; the kernel sits at
// a register knife-edge. This round mirrors the same transform on the
// OTHER serial chain in the softmax round: the 16-element ps accumulation
// (serial depth 16 -> pairwise tree depth 4). f32 add reassoc ~1ulp;
// tolerance has 10x headroom. Single change vs round-17.
// ---------------------------------------------------------------------------
__global__ __launch_bounds__(256, 3) void attn_kernel(
    const _Float16* __restrict__ q_hi, const _Float16* __restrict__ q_lo,
    const _Float16* __restrict__ k16, const _Float16* __restrict__ v16,
    const _Float16* __restrict__ g16, const float* __restrict__ bias_n,
    float* __restrict__ go)
{
    __shared__ _Float16 Khs[64][44];
    __shared__ _Float16 Vts[32][76];     // V^T: [d][kpos_local 0..63]
    __shared__ _Float16 Pb[4][32][76];   // per-wave P, 2 j-tiles per phase

    const int tid  = threadIdx.x;
    const int w    = tid >> 6;
    const int lane = tid & 63;
    const int lg   = lane >> 4, lm = lane & 15;
    const int i = blockIdx.x >> 2, h = blockIdx.x & 3;
    const size_t base = (size_t)i * 256 * 128 + (size_t)h * 32;
    const int j0w = w * 64;

    // Q fragments: direct f16x8 loads from pre-split planes
    f16x8 qh[4], ql[4];
    #pragma unroll
    for (int jt = 0; jt < 4; ++jt) {
        size_t off = base + (size_t)(j0w + jt * 16 + lm) * 128 + lg * 8;
        qh[jt] = *(const f16x8*)(q_hi + off);
        ql[jt] = *(const f16x8*)(q_lo + off);
    }

    float Oacc[2][4][4] = {};            // [dt][jt][rr]: O^T (col=j=lm, row=d)
    float mrow[4], lrow[4];
    #pragma unroll
    for (int jt = 0; jt < 4; ++jt) { mrow[jt] = -1e30f; lrow[jt] = 0.f; }

    const int sr  = tid >> 2;            // staging kpos-local 0..63
    const int sc8 = (tid & 3) * 8;       // staging d col (8-wide)

    f16x8 kpre = *(const f16x8*)(k16 + base + (size_t)sr * 128 + sc8);
    f16x8 vpre = *(const f16x8*)(v16 + base + (size_t)sr * 128 + sc8);

    for (int kc = 0; kc < 256; kc += 64) {
        __syncthreads();
        *(f16x8*)&Khs[sr][sc8] = kpre;
        #pragma unroll
        for (int e = 0; e < 8; ++e) Vts[sc8 + e][sr] = vpre[e];
        __syncthreads();
        if (kc + 64 < 256) {             // prefetch next phase
            kpre = *(const f16x8*)(k16 + base + (size_t)(kc + 64 + sr) * 128 + sc8);
            vpre = *(const f16x8*)(v16 + base + (size_t)(kc + 64 + sr) * 128 + sc8);
        }

        // A-operand frags: K rows t*16+lm (kpos), V^T rows dt*16+lm (d)
        f16x8 kf[4];
        #pragma unroll
        for (int t = 0; t < 4; ++t) kf[t] = *(const f16x8*)&Khs[t * 16 + lm][lg * 8];
        f16x8 vf[2][2];
        #pragma unroll
        for (int dt = 0; dt < 2; ++dt)
            #pragma unroll
            for (int ks = 0; ks < 2; ++ks)
                vf[dt][ks] = *(const f16x8*)&Vts[dt * 16 + lm][ks * 32 + lg * 8];

        // ---- two jt-phases: {QK+softmax for 2 tiles -> Pb; PV for 2 tiles} ----
        #pragma unroll
        for (int jh2 = 0; jh2 < 2; ++jh2) {
            #pragma unroll
            for (int t2 = 0; t2 < 2; ++t2) {
                const int jt = jh2 * 2 + t2;
                const float* bj = bias_n + (size_t)h * NPOS
                                + (size_t)(j0w + jt * 16 + lm) * 256 + kc + lg * 4;
                float s[16];
                #pragma unroll
                for (int t = 0; t < 4; ++t) {
                    float4 bv = *(const float4*)(bj + t * 16);
                    f32x4 c  = {bv.x, bv.y, bv.z, bv.w};
                    f32x4 cl = {0.f, 0.f, 0.f, 0.f};
                    c  = __builtin_amdgcn_mfma_f32_16x16x32_f16(kf[t], qh[jt], c,  0, 0, 0);
                    cl = __builtin_amdgcn_mfma_f32_16x16x32_f16(kf[t], ql[jt], cl, 0, 0, 0);
                    #pragma unroll
                    for (int rr = 0; rr < 4; ++rr)
                        s[t * 4 + rr] = c[rr] + cl[rr] * (1.0f / 2048.0f);
                }
                // pairwise max tree (associative -> bit-identical; fuses to v_max3)
                float m01 = fmaxf(fmaxf(s[0],  s[1]),  fmaxf(s[2],  s[3]));
                float m23 = fmaxf(fmaxf(s[4],  s[5]),  fmaxf(s[6],  s[7]));
                float m45 = fmaxf(fmaxf(s[8],  s[9]),  fmaxf(s[10], s[11]));
                float m67 = fmaxf(fmaxf(s[12], s[13]), fmaxf(s[14], s[15]));
                float mx  = fmaxf(fmaxf(m01, m23), fmaxf(m45, m67));
                mx = fmaxf(mx, __shfl_xor(mx, 16));
                mx = fmaxf(mx, __shfl_xor(mx, 32));
                float mn = fmaxf(mrow[jt], mx);
                float alpha = __expf(mrow[jt] - mn);
                mrow[jt] = mn;
                #pragma unroll
                for (int e = 0; e < 16; ++e) s[e] = __expf(s[e] - mn);
                // pairwise sum tree (depth 16 -> 4; ~1ulp reassoc)
                float pA = (s[0]  + s[1])  + (s[2]  + s[3]);
                float pB = (s[4]  + s[5])  + (s[6]  + s[7]);
                float pC = (s[8]  + s[9])  + (s[10] + s[11]);
                float pD = (s[12] + s[13]) + (s[14] + s[15]);
                float ps = (pA + pB) + (pC + pD);
                ps += __shfl_xor(ps, 16);
                ps += __shfl_xor(ps, 32);
                lrow[jt] = lrow[jt] * alpha + ps;
                #pragma unroll
                for (int dt = 0; dt < 2; ++dt)
                    #pragma unroll
                    for (int rr = 0; rr < 4; ++rr) Oacc[dt][jt][rr] *= alpha;
                #pragma unroll
                for (int t = 0; t < 4; ++t) {
                    f16x4 pv;
                    #pragma unroll
                    for (int rr = 0; rr < 4; ++rr) pv[rr] = (_Float16)s[t * 4 + rr];
                    *(f16x4*)&Pb[w][t2 * 16 + lm][t * 16 + lg * 4] = pv;
                }
            }

            // ---- O^T += V^T * P^T (per-wave Pb; wave DS in-order, no barrier) ----
            #pragma unroll
            for (int t2 = 0; t2 < 2; ++t2) {
                const int jt = jh2 * 2 + t2;
                f16x8 pf0 = *(const f16x8*)&Pb[w][t2 * 16 + lm][lg * 8];
                f16x8 pf1 = *(const f16x8*)&Pb[w][t2 * 16 + lm][32 + lg * 8];
                #pragma unroll
                for (int dt = 0; dt < 2; ++dt) {
                    f32x4 c = {Oacc[dt][jt][0], Oacc[dt][jt][1], Oacc[dt][jt][2], Oacc[dt][jt][3]};
                    c = __builtin_amdgcn_mfma_f32_16x16x32_f16(vf[dt][0], pf0, c, 0, 0, 0);
                    c = __builtin_amdgcn_mfma_f32_16x16x32_f16(vf[dt][1], pf1, c, 0, 0, 0);
                    Oacc[dt][jt][0] = c[0]; Oacc[dt][jt][1] = c[1];
                    Oacc[dt][jt][2] = c[2]; Oacc[dt][jt][3] = c[3];
                }
            }
        }
    }

    // ---- epilogue: normalize, gate (f16), store go f32 ----
    #pragma unroll
    for (int jt = 0; jt < 4; ++jt) {
        const int j = j0w + jt * 16 + lm;
        const float inv = 1.0f / lrow[jt];
        #pragma unroll
        for (int dt = 0; dt < 2; ++dt) {
            f16x4 gv4 = *(const f16x4*)(g16 + base + (size_t)j * 128 + dt * 16 + lg * 4);
            float4 ov;
            ov.x = Oacc[dt][jt][0] * inv * (float)gv4[0];
            ov.y = Oacc[dt][jt][1] * inv * (float)gv4[1];
            ov.z = Oacc[dt][jt][2] * inv * (float)gv4[2];
            ov.w = Oacc[dt][jt][3] * inv * (float)gv4[3];
            *(float4*)(go + base + (size_t)j * 128 + dt * 16 + lg * 4) = ov;
        }
    }
}

// ---------------------------------------------------------------------------
// Kernel C (round-12): out = go @ Wo + bo as MFMA f16 GEMM.  (unchanged)
// ---------------------------------------------------------------------------
__global__ __launch_bounds__(256, 3) void out_proj_kernel(
    const float* __restrict__ go, const _Float16* __restrict__ WoT_hi,
    const float* __restrict__ bo, float* __restrict__ out)
{
    __shared__ _Float16 xh[64][136];
    __shared__ _Float16 xl[64][136];
    __shared__ _Float16 Bh[64][136];

    const int tid = threadIdx.x;
    const int p0  = blockIdx.x * 64;
    const int r   = tid >> 2;          // row 0..63
    const int cb  = (tid & 3) * 32;    // col base (4 threads/row)

    // ---- load 32 go values, split hi/lo into LDS ----
    {
        const float4* pr = (const float4*)(go + (size_t)(p0 + r) * 128 + cb);
        #pragma unroll
        for (int i8 = 0; i8 < 4; ++i8) {
            float4 a = pr[i8 * 2], b = pr[i8 * 2 + 1];
            float v[8] = {a.x, a.y, a.z, a.w, b.x, b.y, b.z, b.w};
            f16x8 hv, lv;
            #pragma unroll
            for (int j = 0; j < 8; ++j) {
                _Float16 h = (_Float16)v[j];
                hv[j] = h;
                lv[j] = (_Float16)((v[j] - (float)h) * 2048.0f);
            }
            *(f16x8*)&xh[r][cb + i8 * 8] = hv;
            *(f16x8*)&xl[r][cb + i8 * 8] = lv;
        }
    }
    __syncthreads();

    const int w  = tid >> 6, l = tid & 63;
    const int lm = l & 15, lg = l >> 4;
    const int arow = w * 16 + lm;

    f16x8 ahf[4], alf[4];
    #pragma unroll
    for (int kt = 0; kt < 4; ++kt) {
        ahf[kt] = *(const f16x8*)&xh[arow][kt * 32 + lg * 8];
        alf[kt] = *(const f16x8*)&xl[arow][kt * 32 + lg * 8];
    }

    #pragma unroll
    for (int chunk = 0; chunk < 2; ++chunk) {
        // issue B-chunk global loads (4 x 16B per thread), then sync before
        // overwriting Bh (chunk 1: prior MFMA ds-reads must be done)
        const _Float16* srch = WoT_hi + (size_t)(chunk * 64) * 128;
        f16x8 breg[4];
        #pragma unroll
        for (int it = 0; it < 4; ++it) {
            int idx = it * 256 + tid;
            breg[it] = *(const f16x8*)(srch + (idx >> 4) * 128 + (idx & 15) * 8);
        }
        if (chunk > 0) __syncthreads();
        #pragma unroll
        for (int it = 0; it < 4; ++it) {
            int idx = it * 256 + tid;
            *(f16x8*)&Bh[idx >> 4][(idx & 15) * 8] = breg[it];
        }
        __syncthreads();

        f32x4 acch[4], accc[4];
        #pragma unroll
        for (int ct = 0; ct < 4; ++ct) {
            acch[ct] = (f32x4){0.f, 0.f, 0.f, 0.f};
            accc[ct] = (f32x4){0.f, 0.f, 0.f, 0.f};
        }
        #pragma unroll
        for (int kt = 0; kt < 4; ++kt) {
            const int koff = kt * 32 + lg * 8;
            #pragma unroll
            for (int ct = 0; ct < 4; ++ct) {
                f16x8 bh = *(const f16x8*)&Bh[ct * 16 + lm][koff];
                acch[ct] = __builtin_amdgcn_mfma_f32_16x16x32_f16(ahf[kt], bh, acch[ct], 0, 0, 0);
                accc[ct] = __builtin_amdgcn_mfma_f32_16x16x32_f16(alf[kt], bh, accc[ct], 0, 0, 0);
            }
        }

        // ---- store: out[p0 + w*16 + lg*4 + rr][chunk*64 + ct*16 + lm] ----
        #pragma unroll
        for (int ct = 0; ct < 4; ++ct) {
            const int col = chunk * 64 + ct * 16 + lm;
            const float bov = bo[col];
            #pragma unroll
            for (int rr = 0; rr < 4; ++rr) {
                const int row = p0 + w * 16 + lg * 4 + rr;
                out[(size_t)row * 128 + col] =
                    acch[ct][rr] + accc[ct][rr] * (1.0f / 2048.0f) + bov;
            }
        }
    }
}

// ---------------------------------------------------------------------------
extern "C" void kernel_launch(void* const* d_in, const int* in_sizes, int n_in,
                              void* d_out, int out_size, void* d_ws, size_t ws_size,
                              hipStream_t stream) {
    const float* pair = (const float*)d_in[0];
    const float* ln_w = (const float*)d_in[1];
    const float* ln_b = (const float*)d_in[2];
    const float* Wq   = (const float*)d_in[3];
    const float* Wk   = (const float*)d_in[4];
    const float* Wv   = (const float*)d_in[5];
    const float* Wb   = (const float*)d_in[6];
    const float* Wg   = (const float*)d_in[7];
    const float* bg   = (const float*)d_in[8];
    const float* Wo   = (const float*)d_in[9];
    const float* bo   = (const float*)d_in[10];

    // workspace: f16 planes q_hi,q_lo,k,v,g (NPOS*128 each) + go f32 + bias_n
    // + WoT_hi (128x128 f16)
    _Float16* q_hi = (_Float16*)d_ws;
    _Float16* q_lo = q_hi + (size_t)NPOS * 128;
    _Float16* k16  = q_lo + (size_t)NPOS * 128;
    _Float16* v16  = k16 + (size_t)NPOS * 128;
    _Float16* g16  = v16 + (size_t)NPOS * 128;
    float* go      = (float*)(g16 + (size_t)NPOS * 128);
    float* bias_n  = go + (size_t)NPOS * 128;
    _Float16* WoT_hi = (_Float16*)(bias_n + 4 * (size_t)NPOS);
    float* out     = (float*)d_out;

    // Transient scratch for transposed hi-plane weights: in d_out
    // (out_proj overwrites all of d_out at the end).
    _Float16* Wt_hi = (_Float16*)d_out;

    hipLaunchKernelGGL(split_w_kernel, dim3(320), dim3(256), 0, stream,
                       Wq, Wk, Wv, Wg, Wo, Wt_hi, WoT_hi);
    hipLaunchKernelGGL(ln_proj_kernel, dim3(1024), dim3(256), 0, stream,
                       pair, ln_w, ln_b, Wb, bg, Wt_hi,
                       q_hi, q_lo, k16, v16, g16, bias_n);
    hipLaunchKernelGGL(attn_kernel, dim3(1024), dim3(256), 0, stream,
                       q_hi, q_lo, k16, v16, g16, bias_n, go);
    hipLaunchKernelGGL(out_proj_kernel, dim3(1024), dim3(256), 0, stream,
                       go, WoT_hi, bo, out);
}

// Round 12
// 231.120 us; speedup vs baseline: 1.0959x; 1.0959x over previous
//
#include <hip/hip_runtime.h>
#include <math.h>

// Sizes (hard-coded per reference): B=1, L=256, D=128, H=4, DH=32
// positions P = L*L = 65536; HD = H*DH = 128
#define NPOS 65536

typedef _Float16 f16x8 __attribute__((ext_vector_type(8)));
typedef _Float16 f16x4 __attribute__((ext_vector_type(4)));
typedef float    f32x4 __attribute__((ext_vector_type(4)));

__device__ __forceinline__ unsigned short f16bits(_Float16 h) {
    return __builtin_bit_cast(unsigned short, h);
}

// ---------------------------------------------------------------------------
// Kernel P: transpose W{q,k,v,g} (fp32 [k=128][n=128]) into f16 hi plane only:
// Wt_hi[n_global=512][k=128]. Also emits WoT_hi[n=128][k=128] for the MFMA
// out_proj. Grid 320 blocks.
// ---------------------------------------------------------------------------
__global__ __launch_bounds__(256) void split_w_kernel(
    const float* __restrict__ Wq, const float* __restrict__ Wk,
    const float* __restrict__ Wv, const float* __restrict__ Wg,
    const float* __restrict__ Wo,
    _Float16* __restrict__ Wt_hi, _Float16* __restrict__ WoT_hi)
{
    int t = blockIdx.x * 256 + threadIdx.x;       // 0..81919
    if (t < 65536) {
        int ng = t >> 7, kk = t & 127;
        int mat = ng >> 7, n = ng & 127;
        const float* W = (mat == 0) ? Wq : (mat == 1) ? Wk : (mat == 2) ? Wv : Wg;
        Wt_hi[t] = (_Float16)W[kk * 128 + n];
    } else {
        int tt = t - 65536;                       // 0..16383
        int n = tt >> 7, kk = tt & 127;
        WoT_hi[tt] = (_Float16)Wo[kk * 128 + n];
    }
}

// ---------------------------------------------------------------------------
// Kernel A (round-7): LN + split-f16(A-side only) MFMA GEMM.  (unchanged)
// ---------------------------------------------------------------------------
__global__ __launch_bounds__(256, 4) void ln_proj_kernel(
    const float* __restrict__ pair, const float* __restrict__ ln_w, const float* __restrict__ ln_b,
    const float* __restrict__ Wb, const float* __restrict__ bg,
    const _Float16* __restrict__ Wt_hi,
    _Float16* __restrict__ q_hi, _Float16* __restrict__ q_lo,
    _Float16* __restrict__ k16, _Float16* __restrict__ v16, _Float16* __restrict__ g16,
    float* __restrict__ bias_n)
{
    __shared__ _Float16 xbuf[2][64][136];   // [0]: xh then Bh; [1]: xl then stg(u32[64][68])
    _Float16 (*xh)[136] = xbuf[0];
    _Float16 (*xl)[136] = xbuf[1];

    const int tid = threadIdx.x;
    const int p0  = blockIdx.x * 64;
    const int r   = tid >> 2;          // row 0..63
    const int cb  = (tid & 3) * 32;    // col base (4 threads/row)

    // ---- load 32 pair values (float4) ----
    float xv[32];
    {
        const float4* pr = (const float4*)(pair + (size_t)(p0 + r) * 128 + cb);
        #pragma unroll
        for (int i = 0; i < 8; ++i) {
            float4 t = pr[i];
            xv[i * 4 + 0] = t.x; xv[i * 4 + 1] = t.y;
            xv[i * 4 + 2] = t.z; xv[i * 4 + 3] = t.w;
        }
    }
    // ---- LN stats across the 4 threads of the row ----
    float sum = 0.f, sq = 0.f;
    #pragma unroll
    for (int i = 0; i < 32; ++i) { sum += xv[i]; sq += xv[i] * xv[i]; }
    sum += __shfl_xor(sum, 1); sq += __shfl_xor(sq, 1);
    sum += __shfl_xor(sum, 2); sq += __shfl_xor(sq, 2);
    float mean = sum * (1.f / 128.f);
    float var  = sq * (1.f / 128.f) - mean * mean;
    float rstd = rsqrtf(var + 1e-5f);

    // ---- normalize, split to f16 hi/lo, store to LDS; bias partial dots ----
    float b0 = 0.f, b1 = 0.f, b2 = 0.f, b3 = 0.f;
    #pragma unroll
    for (int i8 = 0; i8 < 4; ++i8) {
        float4 lw0 = *(const float4*)(ln_w + cb + i8 * 8);
        float4 lw1 = *(const float4*)(ln_w + cb + i8 * 8 + 4);
        float4 lb0 = *(const float4*)(ln_b + cb + i8 * 8);
        float4 lb1 = *(const float4*)(ln_b + cb + i8 * 8 + 4);
        float lw[8] = {lw0.x, lw0.y, lw0.z, lw0.w, lw1.x, lw1.y, lw1.z, lw1.w};
        float lb[8] = {lb0.x, lb0.y, lb0.z, lb0.w, lb1.x, lb1.y, lb1.z, lb1.w};
        f16x8 hv, lv;
        #pragma unroll
        for (int j = 0; j < 8; ++j) {
            int i = i8 * 8 + j;
            float xn = (xv[i] - mean) * rstd * lw[j] + lb[j];
            _Float16 h = (_Float16)xn;
            hv[j] = h;
            lv[j] = (_Float16)((xn - (float)h) * 2048.0f);
            float4 wb = *(const float4*)(Wb + (size_t)(cb + i) * 4);
            b0 = fmaf(xn, wb.x, b0); b1 = fmaf(xn, wb.y, b1);
            b2 = fmaf(xn, wb.z, b2); b3 = fmaf(xn, wb.w, b3);
        }
        *(f16x8*)&xh[r][cb + i8 * 8] = hv;
        *(f16x8*)&xl[r][cb + i8 * 8] = lv;
    }
    // reduce bias dots across the 4 threads of the row, store natural layout
    b0 += __shfl_xor(b0, 1); b1 += __shfl_xor(b1, 1);
    b2 += __shfl_xor(b2, 1); b3 += __shfl_xor(b3, 1);
    b0 += __shfl_xor(b0, 2); b1 += __shfl_xor(b1, 2);
    b2 += __shfl_xor(b2, 2); b3 += __shfl_xor(b3, 2);
    if ((tid & 3) == 0) {
        int p = p0 + r;                        // p = j*256 + kpos
        bias_n[0 * NPOS + p] = b0;
        bias_n[1 * NPOS + p] = b1;
        bias_n[2 * NPOS + p] = b2;
        bias_n[3 * NPOS + p] = b3;
    }
    __syncthreads();

    // ---- A fragments -> registers (16 rows per wave, full K=128) ----
    const int w  = tid >> 6, l = tid & 63;
    const int lm = l & 15, lg = l >> 4;
    const int arow = w * 16 + lm;

    f16x8 ahf[4], alf[4];
    #pragma unroll
    for (int kt = 0; kt < 4; ++kt) {
        ahf[kt] = *(const f16x8*)&xh[arow][kt * 32 + lg * 8];
        alf[kt] = *(const f16x8*)&xl[arow][kt * 32 + lg * 8];
    }

    _Float16 (*Bh)[136] = xbuf[0];                 // B chunk (single plane)
    unsigned* stg = (unsigned*)&xbuf[1][0][0];     // u32 [64][68] (hi | lo<<16)

    const float scale = 0.17677669529663687f;      // 1/sqrt(32)

    for (int chunk = 0; chunk < 8; ++chunk) {
        __syncthreads();   // stg(chunk-1) writes visible; Bh frag-reads done

        // issue B-chunk global loads (4 x 16B per thread)
        const _Float16* srch = Wt_hi + (size_t)(chunk * 64) * 128;
        f16x8 breg[4];
        #pragma unroll
        for (int it = 0; it < 4; ++it) {
            int idx = it * 256 + tid;
            breg[it] = *(const f16x8*)(srch + (idx >> 4) * 128 + (idx & 15) * 8);
        }

        // store previous chunk's outputs from stg (overlaps B-load latency)
        if (chunk > 0) {
            const int pm = (chunk - 1) >> 1, pcol = ((chunk - 1) & 1) * 64;
            #pragma unroll
            for (int it = 0; it < 4; ++it) {
                int idx = it * 256 + tid;
                int row = idx >> 4, c4 = (idx & 15) * 4;
                uint4 pk = *(const uint4*)&stg[row * 68 + c4];
                ushort4 hv = make_ushort4((unsigned short)(pk.x & 0xffff),
                                          (unsigned short)(pk.y & 0xffff),
                                          (unsigned short)(pk.z & 0xffff),
                                          (unsigned short)(pk.w & 0xffff));
                size_t off = (size_t)(p0 + row) * 128 + pcol + c4;
                if (pm == 0) {
                    *(ushort4*)(q_hi + off) = hv;
                    ushort4 lv = make_ushort4((unsigned short)(pk.x >> 16),
                                              (unsigned short)(pk.y >> 16),
                                              (unsigned short)(pk.z >> 16),
                                              (unsigned short)(pk.w >> 16));
                    *(ushort4*)(q_lo + off) = lv;
                } else if (pm == 1) *(ushort4*)(k16 + off) = hv;
                else if   (pm == 2) *(ushort4*)(v16 + off) = hv;
                else                *(ushort4*)(g16 + off) = hv;
            }
        }

        // write B chunk to LDS
        #pragma unroll
        for (int it = 0; it < 4; ++it) {
            int idx = it * 256 + tid;
            *(f16x8*)&Bh[idx >> 4][(idx & 15) * 8] = breg[it];
        }
        __syncthreads();   // B ready; stg free for rewrite

        // ---- MFMA: 4 col-tiles x 4 kt x 2 (x-split only) ----
        const int mat = chunk >> 1;
        f32x4 acch[4], accc[4];
        #pragma unroll
        for (int ct = 0; ct < 4; ++ct) {
            acch[ct] = (f32x4){0.f, 0.f, 0.f, 0.f};
            accc[ct] = (f32x4){0.f, 0.f, 0.f, 0.f};
        }
        #pragma unroll
        for (int kt = 0; kt < 4; ++kt) {
            const int koff = kt * 32 + lg * 8;
            #pragma unroll
            for (int ct = 0; ct < 4; ++ct) {
                f16x8 bh = *(const f16x8*)&Bh[ct * 16 + lm][koff];
                acch[ct] = __builtin_amdgcn_mfma_f32_16x16x32_f16(ahf[kt], bh, acch[ct], 0, 0, 0);
                accc[ct] = __builtin_amdgcn_mfma_f32_16x16x32_f16(alf[kt], bh, accc[ct], 0, 0, 0);
            }
        }

        // ---- epilogue math -> stg (packed u32) ----
        const int colhalf = (chunk & 1) * 64;
        #pragma unroll
        for (int ct = 0; ct < 4; ++ct) {
            const int col = ct * 16 + lm;
            float bgv = (mat == 3) ? bg[colhalf + col] : 0.f;
            #pragma unroll
            for (int rr = 0; rr < 4; ++rr) {
                float val = acch[ct][rr] + accc[ct][rr] * (1.0f / 2048.0f);
                if (mat == 0) val *= scale;
                if (mat == 3) val = 1.f / (1.f + __expf(-(val + bgv)));
                _Float16 h = (_Float16)val;
                unsigned pk = f16bits(h);
                if (mat == 0) {
                    _Float16 lo = (_Float16)((val - (float)h) * 2048.0f);
                    pk |= ((unsigned)f16bits(lo)) << 16;
                }
                stg[(w * 16 + lg * 4 + rr) * 68 + col] = pk;
            }
        }
    }

    // ---- final chunk store ----
    __syncthreads();
    {
        #pragma unroll
        for (int it = 0; it < 4; ++it) {
            int idx = it * 256 + tid;
            int row = idx >> 4, c4 = (idx & 15) * 4;
            uint4 pk = *(const uint4*)&stg[row * 68 + c4];
            ushort4 hv = make_ushort4((unsigned short)(pk.x & 0xffff),
                                      (unsigned short)(pk.y & 0xffff),
                                      (unsigned short)(pk.z & 0xffff),
                                      (unsigned short)(pk.w & 0xffff));
            *(ushort4*)(g16 + (size_t)(p0 + row) * 128 + 64 + c4) = hv;
        }
    }
}

// ---------------------------------------------------------------------------
// Kernel B (round-19 = EXACT round-10 revert): proven best attn artifact
// (77us steady, FETCH 90MB / WRITE 50MB near-ideal, 84 VGPR, total 230.2us).
// Round-11 post-mortem: the sum-tree regressed (102us, FETCH 122 / WRITE
// 84MB — partial spill returned): its 4 live partials pushed peak liveness
// back over the allocator knife-edge. Mechanism now confirmed over rounds
// 10+11: small attn source edits swing +-25us via allocation placement,
// not chain depth. This source (with tree-max, serial sum) is the
// measured-good allocation — frozen.
// Session lever map (all counter-refuted): launch-bounds 4/5 (spill),
// LDS-shrink (no occupancy gain, register-capped), 1-wave blocks (L2
// locality loss + staging serialization), jt-halving (spill), dbuf x2
// (liveness spill), setprio (starves co-resident staging), sum-tree
// (allocator tip). Wins banked: tree-max softmax (-18us), MFMA out_proj
// (-30us), fused-PV 2-phase jt (LDS 49->30KB).
// ---------------------------------------------------------------------------
__global__ __launch_bounds__(256, 3) void attn_kernel(
    const _Float16* __restrict__ q_hi, const _Float16* __restrict__ q_lo,
    const _Float16* __restrict__ k16, const _Float16* __restrict__ v16,
    const _Float16* __restrict__ g16, const float* __restrict__ bias_n,
    float* __restrict__ go)
{
    __shared__ _Float16 Khs[64][44];
    __shared__ _Float16 Vts[32][76];     // V^T: [d][kpos_local 0..63]
    __shared__ _Float16 Pb[4][32][76];   // per-wave P, 2 j-tiles per phase

    const int tid  = threadIdx.x;
    const int w    = tid >> 6;
    const int lane = tid & 63;
    const int lg   = lane >> 4, lm = lane & 15;
    const int i = blockIdx.x >> 2, h = blockIdx.x & 3;
    const size_t base = (size_t)i * 256 * 128 + (size_t)h * 32;
    const int j0w = w * 64;

    // Q fragments: direct f16x8 loads from pre-split planes
    f16x8 qh[4], ql[4];
    #pragma unroll
    for (int jt = 0; jt < 4; ++jt) {
        size_t off = base + (size_t)(j0w + jt * 16 + lm) * 128 + lg * 8;
        qh[jt] = *(const f16x8*)(q_hi + off);
        ql[jt] = *(const f16x8*)(q_lo + off);
    }

    float Oacc[2][4][4] = {};            // [dt][jt][rr]: O^T (col=j=lm, row=d)
    float mrow[4], lrow[4];
    #pragma unroll
    for (int jt = 0; jt < 4; ++jt) { mrow[jt] = -1e30f; lrow[jt] = 0.f; }

    const int sr  = tid >> 2;            // staging kpos-local 0..63
    const int sc8 = (tid & 3) * 8;       // staging d col (8-wide)

    f16x8 kpre = *(const f16x8*)(k16 + base + (size_t)sr * 128 + sc8);
    f16x8 vpre = *(const f16x8*)(v16 + base + (size_t)sr * 128 + sc8);

    for (int kc = 0; kc < 256; kc += 64) {
        __syncthreads();
        *(f16x8*)&Khs[sr][sc8] = kpre;
        #pragma unroll
        for (int e = 0; e < 8; ++e) Vts[sc8 + e][sr] = vpre[e];
        __syncthreads();
        if (kc + 64 < 256) {             // prefetch next phase
            kpre = *(const f16x8*)(k16 + base + (size_t)(kc + 64 + sr) * 128 + sc8);
            vpre = *(const f16x8*)(v16 + base + (size_t)(kc + 64 + sr) * 128 + sc8);
        }

        // A-operand frags: K rows t*16+lm (kpos), V^T rows dt*16+lm (d)
        f16x8 kf[4];
        #pragma unroll
        for (int t = 0; t < 4; ++t) kf[t] = *(const f16x8*)&Khs[t * 16 + lm][lg * 8];
        f16x8 vf[2][2];
        #pragma unroll
        for (int dt = 0; dt < 2; ++dt)
            #pragma unroll
            for (int ks = 0; ks < 2; ++ks)
                vf[dt][ks] = *(const f16x8*)&Vts[dt * 16 + lm][ks * 32 + lg * 8];

        // ---- two jt-phases: {QK+softmax for 2 tiles -> Pb; PV for 2 tiles} ----
        #pragma unroll
        for (int jh2 = 0; jh2 < 2; ++jh2) {
            #pragma unroll
            for (int t2 = 0; t2 < 2; ++t2) {
                const int jt = jh2 * 2 + t2;
                const float* bj = bias_n + (size_t)h * NPOS
                                + (size_t)(j0w + jt * 16 + lm) * 256 + kc + lg * 4;
                float s[16];
                #pragma unroll
                for (int t = 0; t < 4; ++t) {
                    float4 bv = *(const float4*)(bj + t * 16);
                    f32x4 c  = {bv.x, bv.y, bv.z, bv.w};
                    f32x4 cl = {0.f, 0.f, 0.f, 0.f};
                    c  = __builtin_amdgcn_mfma_f32_16x16x32_f16(kf[t], qh[jt], c,  0, 0, 0);
                    cl = __builtin_amdgcn_mfma_f32_16x16x32_f16(kf[t], ql[jt], cl, 0, 0, 0);
                    #pragma unroll
                    for (int rr = 0; rr < 4; ++rr)
                        s[t * 4 + rr] = c[rr] + cl[rr] * (1.0f / 2048.0f);
                }
                // pairwise max tree (associative -> bit-identical; fuses to v_max3)
                float m01 = fmaxf(fmaxf(s[0],  s[1]),  fmaxf(s[2],  s[3]));
                float m23 = fmaxf(fmaxf(s[4],  s[5]),  fmaxf(s[6],  s[7]));
                float m45 = fmaxf(fmaxf(s[8],  s[9]),  fmaxf(s[10], s[11]));
                float m67 = fmaxf(fmaxf(s[12], s[13]), fmaxf(s[14], s[15]));
                float mx  = fmaxf(fmaxf(m01, m23), fmaxf(m45, m67));
                mx = fmaxf(mx, __shfl_xor(mx, 16));
                mx = fmaxf(mx, __shfl_xor(mx, 32));
                float mn = fmaxf(mrow[jt], mx);
                float alpha = __expf(mrow[jt] - mn);
                mrow[jt] = mn;
                float ps = 0.f;
                #pragma unroll
                for (int e = 0; e < 16; ++e) { s[e] = __expf(s[e] - mn); ps += s[e]; }
                ps += __shfl_xor(ps, 16);
                ps += __shfl_xor(ps, 32);
                lrow[jt] = lrow[jt] * alpha + ps;
                #pragma unroll
                for (int dt = 0; dt < 2; ++dt)
                    #pragma unroll
                    for (int rr = 0; rr < 4; ++rr) Oacc[dt][jt][rr] *= alpha;
                #pragma unroll
                for (int t = 0; t < 4; ++t) {
                    f16x4 pv;
                    #pragma unroll
                    for (int rr = 0; rr < 4; ++rr) pv[rr] = (_Float16)s[t * 4 + rr];
                    *(f16x4*)&Pb[w][t2 * 16 + lm][t * 16 + lg * 4] = pv;
                }
            }

            // ---- O^T += V^T * P^T (per-wave Pb; wave DS in-order, no barrier) ----
            #pragma unroll
            for (int t2 = 0; t2 < 2; ++t2) {
                const int jt = jh2 * 2 + t2;
                f16x8 pf0 = *(const f16x8*)&Pb[w][t2 * 16 + lm][lg * 8];
                f16x8 pf1 = *(const f16x8*)&Pb[w][t2 * 16 + lm][32 + lg * 8];
                #pragma unroll
                for (int dt = 0; dt < 2; ++dt) {
                    f32x4 c = {Oacc[dt][jt][0], Oacc[dt][jt][1], Oacc[dt][jt][2], Oacc[dt][jt][3]};
                    c = __builtin_amdgcn_mfma_f32_16x16x32_f16(vf[dt][0], pf0, c, 0, 0, 0);
                    c = __builtin_amdgcn_mfma_f32_16x16x32_f16(vf[dt][1], pf1, c, 0, 0, 0);
                    Oacc[dt][jt][0] = c[0]; Oacc[dt][jt][1] = c[1];
                    Oacc[dt][jt][2] = c[2]; Oacc[dt][jt][3] = c[3];
                }
            }
        }
    }

    // ---- epilogue: normalize, gate (f16), store go f32 ----
    #pragma unroll
    for (int jt = 0; jt < 4; ++jt) {
        const int j = j0w + jt * 16 + lm;
        const float inv = 1.0f / lrow[jt];
        #pragma unroll
        for (int dt = 0; dt < 2; ++dt) {
            f16x4 gv4 = *(const f16x4*)(g16 + base + (size_t)j * 128 + dt * 16 + lg * 4);
            float4 ov;
            ov.x = Oacc[dt][jt][0] * inv * (float)gv4[0];
            ov.y = Oacc[dt][jt][1] * inv * (float)gv4[1];
            ov.z = Oacc[dt][jt][2] * inv * (float)gv4[2];
            ov.w = Oacc[dt][jt][3] * inv * (float)gv4[3];
            *(float4*)(go + base + (size_t)j * 128 + dt * 16 + lg * 4) = ov;
        }
    }
}

// ---------------------------------------------------------------------------
// Kernel C (round-12): out = go @ Wo + bo as MFMA f16 GEMM.  (unchanged)
// ---------------------------------------------------------------------------
__global__ __launch_bounds__(256, 3) void out_proj_kernel(
    const float* __restrict__ go, const _Float16* __restrict__ WoT_hi,
    const float* __restrict__ bo, float* __restrict__ out)
{
    __shared__ _Float16 xh[64][136];
    __shared__ _Float16 xl[64][136];
    __shared__ _Float16 Bh[64][136];

    const int tid = threadIdx.x;
    const int p0  = blockIdx.x * 64;
    const int r   = tid >> 2;          // row 0..63
    const int cb  = (tid & 3) * 32;    // col base (4 threads/row)

    // ---- load 32 go values, split hi/lo into LDS ----
    {
        const float4* pr = (const float4*)(go + (size_t)(p0 + r) * 128 + cb);
        #pragma unroll
        for (int i8 = 0; i8 < 4; ++i8) {
            float4 a = pr[i8 * 2], b = pr[i8 * 2 + 1];
            float v[8] = {a.x, a.y, a.z, a.w, b.x, b.y, b.z, b.w};
            f16x8 hv, lv;
            #pragma unroll
            for (int j = 0; j < 8; ++j) {
                _Float16 h = (_Float16)v[j];
                hv[j] = h;
                lv[j] = (_Float16)((v[j] - (float)h) * 2048.0f);
            }
            *(f16x8*)&xh[r][cb + i8 * 8] = hv;
            *(f16x8*)&xl[r][cb + i8 * 8] = lv;
        }
    }
    __syncthreads();

    const int w  = tid >> 6, l = tid & 63;
    const int lm = l & 15, lg = l >> 4;
    const int arow = w * 16 + lm;

    f16x8 ahf[4], alf[4];
    #pragma unroll
    for (int kt = 0; kt < 4; ++kt) {
        ahf[kt] = *(const f16x8*)&xh[arow][kt * 32 + lg * 8];
        alf[kt] = *(const f16x8*)&xl[arow][kt * 32 + lg * 8];
    }

    #pragma unroll
    for (int chunk = 0; chunk < 2; ++chunk) {
        // issue B-chunk global loads (4 x 16B per thread), then sync before
        // overwriting Bh (chunk 1: prior MFMA ds-reads must be done)
        const _Float16* srch = WoT_hi + (size_t)(chunk * 64) * 128;
        f16x8 breg[4];
        #pragma unroll
        for (int it = 0; it < 4; ++it) {
            int idx = it * 256 + tid;
            breg[it] = *(const f16x8*)(srch + (idx >> 4) * 128 + (idx & 15) * 8);
        }
        if (chunk > 0) __syncthreads();
        #pragma unroll
        for (int it = 0; it < 4; ++it) {
            int idx = it * 256 + tid;
            *(f16x8*)&Bh[idx >> 4][(idx & 15) * 8] = breg[it];
        }
        __syncthreads();

        f32x4 acch[4], accc[4];
        #pragma unroll
        for (int ct = 0; ct < 4; ++ct) {
            acch[ct] = (f32x4){0.f, 0.f, 0.f, 0.f};
            accc[ct] = (f32x4){0.f, 0.f, 0.f, 0.f};
        }
        #pragma unroll
        for (int kt = 0; kt < 4; ++kt) {
            const int koff = kt * 32 + lg * 8;
            #pragma unroll
            for (int ct = 0; ct < 4; ++ct) {
                f16x8 bh = *(const f16x8*)&Bh[ct * 16 + lm][koff];
                acch[ct] = __builtin_amdgcn_mfma_f32_16x16x32_f16(ahf[kt], bh, acch[ct], 0, 0, 0);
                accc[ct] = __builtin_amdgcn_mfma_f32_16x16x32_f16(alf[kt], bh, accc[ct], 0, 0, 0);
            }
        }

        // ---- store: out[p0 + w*16 + lg*4 + rr][chunk*64 + ct*16 + lm] ----
        #pragma unroll
        for (int ct = 0; ct < 4; ++ct) {
            const int col = chunk * 64 + ct * 16 + lm;
            const float bov = bo[col];
            #pragma unroll
            for (int rr = 0; rr < 4; ++rr) {
                const int row = p0 + w * 16 + lg * 4 + rr;
                out[(size_t)row * 128 + col] =
                    acch[ct][rr] + accc[ct][rr] * (1.0f / 2048.0f) + bov;
            }
        }
    }
}

// ---------------------------------------------------------------------------
extern "C" void kernel_launch(void* const* d_in, const int* in_sizes, int n_in,
                              void* d_out, int out_size, void* d_ws, size_t ws_size,
                              hipStream_t stream) {
    const float* pair = (const float*)d_in[0];
    const float* ln_w = (const float*)d_in[1];
    const float* ln_b = (const float*)d_in[2];
    const float* Wq   = (const float*)d_in[3];
    const float* Wk   = (const float*)d_in[4];
    const float* Wv   = (const float*)d_in[5];
    const float* Wb   = (const float*)d_in[6];
    const float* Wg   = (const float*)d_in[7];
    const float* bg   = (const float*)d_in[8];
    const float* Wo   = (const float*)d_in[9];
    const float* bo   = (const float*)d_in[10];

    // workspace: f16 planes q_hi,q_lo,k,v,g (NPOS*128 each) + go f32 + bias_n
    // + WoT_hi (128x128 f16)
    _Float16* q_hi = (_Float16*)d_ws;
    _Float16* q_lo = q_hi + (size_t)NPOS * 128;
    _Float16* k16  = q_lo + (size_t)NPOS * 128;
    _Float16* v16  = k16 + (size_t)NPOS * 128;
    _Float16* g16  = v16 + (size_t)NPOS * 128;
    float* go      = (float*)(g16 + (size_t)NPOS * 128);
    float* bias_n  = go + (size_t)NPOS * 128;
    _Float16* WoT_hi = (_Float16*)(bias_n + 4 * (size_t)NPOS);
    float* out     = (float*)d_out;

    // Transient scratch for transposed hi-plane weights: in d_out
    // (out_proj overwrites all of d_out at the end).
    _Float16* Wt_hi = (_Float16*)d_out;

    hipLaunchKernelGGL(split_w_kernel, dim3(320), dim3(256), 0, stream,
                       Wq, Wk, Wv, Wg, Wo, Wt_hi, WoT_hi);
    hipLaunchKernelGGL(ln_proj_kernel, dim3(1024), dim3(256), 0, stream,
                       pair, ln_w, ln_b, Wb, bg, Wt_hi,
                       q_hi, q_lo, k16, v16, g16, bias_n);
    hipLaunchKernelGGL(attn_kernel, dim3(1024), dim3(256), 0, stream,
                       q_hi, q_lo, k16, v16, g16, bias_n, go);
    hipLaunchKernelGGL(out_proj_kernel, dim3(1024), dim3(256), 0, stream,
                       go, WoT_hi, bo, out);
}

// Round 13
// 228.881 us; speedup vs baseline: 1.1066x; 1.0098x over previous
//
#include <hip/hip_runtime.h>
#include <math.h>

// Sizes (hard-coded per reference): B=1, L=256, D=128, H=4, DH=32
// positions P = L*L = 65536; HD = H*DH = 128
#define NPOS 65536

typedef _Float16 f16x8 __attribute__((ext_vector_type(8)));
typedef _Float16 f16x4 __attribute__((ext_vector_type(4)));
typedef float    f32x4 __attribute__((ext_vector_type(4)));

__device__ __forceinline__ unsigned short f16bits(_Float16 h) {
    return __builtin_bit_cast(unsigned short, h);
}

// ---------------------------------------------------------------------------
// Kernel P: transpose W{q,k,v,g} (fp32 [k=128][n=128]) into f16 hi plane only:
// Wt_hi[n_global=512][k=128]. Also emits WoT_hi[n=128][k=128] for the MFMA
// out_proj. Grid 320 blocks.
// ---------------------------------------------------------------------------
__global__ __launch_bounds__(256) void split_w_kernel(
    const float* __restrict__ Wq, const float* __restrict__ Wk,
    const float* __restrict__ Wv, const float* __restrict__ Wg,
    const float* __restrict__ Wo,
    _Float16* __restrict__ Wt_hi, _Float16* __restrict__ WoT_hi)
{
    int t = blockIdx.x * 256 + threadIdx.x;       // 0..81919
    if (t < 65536) {
        int ng = t >> 7, kk = t & 127;
        int mat = ng >> 7, n = ng & 127;
        const float* W = (mat == 0) ? Wq : (mat == 1) ? Wk : (mat == 2) ? Wv : Wg;
        Wt_hi[t] = (_Float16)W[kk * 128 + n];
    } else {
        int tt = t - 65536;                       // 0..16383
        int n = tt >> 7, kk = tt & 127;
        WoT_hi[tt] = (_Float16)Wo[kk * 128 + n];
    }
}

// ---------------------------------------------------------------------------
// Kernel A (round-7): LN + split-f16(A-side only) MFMA GEMM.  (unchanged)
// ---------------------------------------------------------------------------
__global__ __launch_bounds__(256, 4) void ln_proj_kernel(
    const float* __restrict__ pair, const float* __restrict__ ln_w, const float* __restrict__ ln_b,
    const float* __restrict__ Wb, const float* __restrict__ bg,
    const _Float16* __restrict__ Wt_hi,
    _Float16* __restrict__ q_hi, _Float16* __restrict__ q_lo,
    _Float16* __restrict__ k16, _Float16* __restrict__ v16, _Float16* __restrict__ g16,
    float* __restrict__ bias_n)
{
    __shared__ _Float16 xbuf[2][64][136];   // [0]: xh then Bh; [1]: xl then stg(u32[64][68])
    _Float16 (*xh)[136] = xbuf[0];
    _Float16 (*xl)[136] = xbuf[1];

    const int tid = threadIdx.x;
    const int p0  = blockIdx.x * 64;
    const int r   = tid >> 2;          // row 0..63
    const int cb  = (tid & 3) * 32;    // col base (4 threads/row)

    // ---- load 32 pair values (float4) ----
    float xv[32];
    {
        const float4* pr = (const float4*)(pair + (size_t)(p0 + r) * 128 + cb);
        #pragma unroll
        for (int i = 0; i < 8; ++i) {
            float4 t = pr[i];
            xv[i * 4 + 0] = t.x; xv[i * 4 + 1] = t.y;
            xv[i * 4 + 2] = t.z; xv[i * 4 + 3] = t.w;
        }
    }
    // ---- LN stats across the 4 threads of the row ----
    float sum = 0.f, sq = 0.f;
    #pragma unroll
    for (int i = 0; i < 32; ++i) { sum += xv[i]; sq += xv[i] * xv[i]; }
    sum += __shfl_xor(sum, 1); sq += __shfl_xor(sq, 1);
    sum += __shfl_xor(sum, 2); sq += __shfl_xor(sq, 2);
    float mean = sum * (1.f / 128.f);
    float var  = sq * (1.f / 128.f) - mean * mean;
    float rstd = rsqrtf(var + 1e-5f);

    // ---- normalize, split to f16 hi/lo, store to LDS; bias partial dots ----
    float b0 = 0.f, b1 = 0.f, b2 = 0.f, b3 = 0.f;
    #pragma unroll
    for (int i8 = 0; i8 < 4; ++i8) {
        float4 lw0 = *(const float4*)(ln_w + cb + i8 * 8);
        float4 lw1 = *(const float4*)(ln_w + cb + i8 * 8 + 4);
        float4 lb0 = *(const float4*)(ln_b + cb + i8 * 8);
        float4 lb1 = *(const float4*)(ln_b + cb + i8 * 8 + 4);
        float lw[8] = {lw0.x, lw0.y, lw0.z, lw0.w, lw1.x, lw1.y, lw1.z, lw1.w};
        float lb[8] = {lb0.x, lb0.y, lb0.z, lb0.w, lb1.x, lb1.y, lb1.z, lb1.w};
        f16x8 hv, lv;
        #pragma unroll
        for (int j = 0; j < 8; ++j) {
            int i = i8 * 8 + j;
            float xn = (xv[i] - mean) * rstd * lw[j] + lb[j];
            _Float16 h = (_Float16)xn;
            hv[j] = h;
            lv[j] = (_Float16)((xn - (float)h) * 2048.0f);
            float4 wb = *(const float4*)(Wb + (size_t)(cb + i) * 4);
            b0 = fmaf(xn, wb.x, b0); b1 = fmaf(xn, wb.y, b1);
            b2 = fmaf(xn, wb.z, b2); b3 = fmaf(xn, wb.w, b3);
        }
        *(f16x8*)&xh[r][cb + i8 * 8] = hv;
        *(f16x8*)&xl[r][cb + i8 * 8] = lv;
    }
    // reduce bias dots across the 4 threads of the row, store natural layout
    b0 += __shfl_xor(b0, 1); b1 += __shfl_xor(b1, 1);
    b2 += __shfl_xor(b2, 1); b3 += __shfl_xor(b3, 1);
    b0 += __shfl_xor(b0, 2); b1 += __shfl_xor(b1, 2);
    b2 += __shfl_xor(b2, 2); b3 += __shfl_xor(b3, 2);
    if ((tid & 3) == 0) {
        int p = p0 + r;                        // p = j*256 + kpos
        bias_n[0 * NPOS + p] = b0;
        bias_n[1 * NPOS + p] = b1;
        bias_n[2 * NPOS + p] = b2;
        bias_n[3 * NPOS + p] = b3;
    }
    __syncthreads();

    // ---- A fragments -> registers (16 rows per wave, full K=128) ----
    const int w  = tid >> 6, l = tid & 63;
    const int lm = l & 15, lg = l >> 4;
    const int arow = w * 16 + lm;

    f16x8 ahf[4], alf[4];
    #pragma unroll
    for (int kt = 0; kt < 4; ++kt) {
        ahf[kt] = *(const f16x8*)&xh[arow][kt * 32 + lg * 8];
        alf[kt] = *(const f16x8*)&xl[arow][kt * 32 + lg * 8];
    }

    _Float16 (*Bh)[136] = xbuf[0];                 // B chunk (single plane)
    unsigned* stg = (unsigned*)&xbuf[1][0][0];     // u32 [64][68] (hi | lo<<16)

    const float scale = 0.17677669529663687f;      // 1/sqrt(32)

    for (int chunk = 0; chunk < 8; ++chunk) {
        __syncthreads();   // stg(chunk-1) writes visible; Bh frag-reads done

        // issue B-chunk global loads (4 x 16B per thread)
        const _Float16* srch = Wt_hi + (size_t)(chunk * 64) * 128;
        f16x8 breg[4];
        #pragma unroll
        for (int it = 0; it < 4; ++it) {
            int idx = it * 256 + tid;
            breg[it] = *(const f16x8*)(srch + (idx >> 4) * 128 + (idx & 15) * 8);
        }

        // store previous chunk's outputs from stg (overlaps B-load latency)
        if (chunk > 0) {
            const int pm = (chunk - 1) >> 1, pcol = ((chunk - 1) & 1) * 64;
            #pragma unroll
            for (int it = 0; it < 4; ++it) {
                int idx = it * 256 + tid;
                int row = idx >> 4, c4 = (idx & 15) * 4;
                uint4 pk = *(const uint4*)&stg[row * 68 + c4];
                ushort4 hv = make_ushort4((unsigned short)(pk.x & 0xffff),
                                          (unsigned short)(pk.y & 0xffff),
                                          (unsigned short)(pk.z & 0xffff),
                                          (unsigned short)(pk.w & 0xffff));
                size_t off = (size_t)(p0 + row) * 128 + pcol + c4;
                if (pm == 0) {
                    *(ushort4*)(q_hi + off) = hv;
                    ushort4 lv = make_ushort4((unsigned short)(pk.x >> 16),
                                              (unsigned short)(pk.y >> 16),
                                              (unsigned short)(pk.z >> 16),
                                              (unsigned short)(pk.w >> 16));
                    *(ushort4*)(q_lo + off) = lv;
                } else if (pm == 1) *(ushort4*)(k16 + off) = hv;
                else if   (pm == 2) *(ushort4*)(v16 + off) = hv;
                else                *(ushort4*)(g16 + off) = hv;
            }
        }

        // write B chunk to LDS
        #pragma unroll
        for (int it = 0; it < 4; ++it) {
            int idx = it * 256 + tid;
            *(f16x8*)&Bh[idx >> 4][(idx & 15) * 8] = breg[it];
        }
        __syncthreads();   // B ready; stg free for rewrite

        // ---- MFMA: 4 col-tiles x 4 kt x 2 (x-split only) ----
        const int mat = chunk >> 1;
        f32x4 acch[4], accc[4];
        #pragma unroll
        for (int ct = 0; ct < 4; ++ct) {
            acch[ct] = (f32x4){0.f, 0.f, 0.f, 0.f};
            accc[ct] = (f32x4){0.f, 0.f, 0.f, 0.f};
        }
        #pragma unroll
        for (int kt = 0; kt < 4; ++kt) {
            const int koff = kt * 32 + lg * 8;
            #pragma unroll
            for (int ct = 0; ct < 4; ++ct) {
                f16x8 bh = *(const f16x8*)&Bh[ct * 16 + lm][koff];
                acch[ct] = __builtin_amdgcn_mfma_f32_16x16x32_f16(ahf[kt], bh, acch[ct], 0, 0, 0);
                accc[ct] = __builtin_amdgcn_mfma_f32_16x16x32_f16(alf[kt], bh, accc[ct], 0, 0, 0);
            }
        }

        // ---- epilogue math -> stg (packed u32) ----
        const int colhalf = (chunk & 1) * 64;
        #pragma unroll
        for (int ct = 0; ct < 4; ++ct) {
            const int col = ct * 16 + lm;
            float bgv = (mat == 3) ? bg[colhalf + col] : 0.f;
            #pragma unroll
            for (int rr = 0; rr < 4; ++rr) {
                float val = acch[ct][rr] + accc[ct][rr] * (1.0f / 2048.0f);
                if (mat == 0) val *= scale;
                if (mat == 3) val = 1.f / (1.f + __expf(-(val + bgv)));
                _Float16 h = (_Float16)val;
                unsigned pk = f16bits(h);
                if (mat == 0) {
                    _Float16 lo = (_Float16)((val - (float)h) * 2048.0f);
                    pk |= ((unsigned)f16bits(lo)) << 16;
                }
                stg[(w * 16 + lg * 4 + rr) * 68 + col] = pk;
            }
        }
    }

    // ---- final chunk store ----
    __syncthreads();
    {
        #pragma unroll
        for (int it = 0; it < 4; ++it) {
            int idx = it * 256 + tid;
            int row = idx >> 4, c4 = (idx & 15) * 4;
            uint4 pk = *(const uint4*)&stg[row * 68 + c4];
            ushort4 hv = make_ushort4((unsigned short)(pk.x & 0xffff),
                                      (unsigned short)(pk.y & 0xffff),
                                      (unsigned short)(pk.z & 0xffff),
                                      (unsigned short)(pk.w & 0xffff));
            *(ushort4*)(g16 + (size_t)(p0 + row) * 128 + 64 + c4) = hv;
        }
    }
}

// ---------------------------------------------------------------------------
// Kernel B (round-19 = round-10 artifact, FROZEN): proven best attn
// (77us steady, FETCH 90MB / WRITE 50MB near-ideal, 84 VGPR).
// Reproduced twice (230.2 / 231.1 total). Register knife-edge documented
// over rounds 10-11; source must not be perturbed.
// ---------------------------------------------------------------------------
__global__ __launch_bounds__(256, 3) void attn_kernel(
    const _Float16* __restrict__ q_hi, const _Float16* __restrict__ q_lo,
    const _Float16* __restrict__ k16, const _Float16* __restrict__ v16,
    const _Float16* __restrict__ g16, const float* __restrict__ bias_n,
    float* __restrict__ go)
{
    __shared__ _Float16 Khs[64][44];
    __shared__ _Float16 Vts[32][76];     // V^T: [d][kpos_local 0..63]
    __shared__ _Float16 Pb[4][32][76];   // per-wave P, 2 j-tiles per phase

    const int tid  = threadIdx.x;
    const int w    = tid >> 6;
    const int lane = tid & 63;
    const int lg   = lane >> 4, lm = lane & 15;
    const int i = blockIdx.x >> 2, h = blockIdx.x & 3;
    const size_t base = (size_t)i * 256 * 128 + (size_t)h * 32;
    const int j0w = w * 64;

    // Q fragments: direct f16x8 loads from pre-split planes
    f16x8 qh[4], ql[4];
    #pragma unroll
    for (int jt = 0; jt < 4; ++jt) {
        size_t off = base + (size_t)(j0w + jt * 16 + lm) * 128 + lg * 8;
        qh[jt] = *(const f16x8*)(q_hi + off);
        ql[jt] = *(const f16x8*)(q_lo + off);
    }

    float Oacc[2][4][4] = {};            // [dt][jt][rr]: O^T (col=j=lm, row=d)
    float mrow[4], lrow[4];
    #pragma unroll
    for (int jt = 0; jt < 4; ++jt) { mrow[jt] = -1e30f; lrow[jt] = 0.f; }

    const int sr  = tid >> 2;            // staging kpos-local 0..63
    const int sc8 = (tid & 3) * 8;       // staging d col (8-wide)

    f16x8 kpre = *(const f16x8*)(k16 + base + (size_t)sr * 128 + sc8);
    f16x8 vpre = *(const f16x8*)(v16 + base + (size_t)sr * 128 + sc8);

    for (int kc = 0; kc < 256; kc += 64) {
        __syncthreads();
        *(f16x8*)&Khs[sr][sc8] = kpre;
        #pragma unroll
        for (int e = 0; e < 8; ++e) Vts[sc8 + e][sr] = vpre[e];
        __syncthreads();
        if (kc + 64 < 256) {             // prefetch next phase
            kpre = *(const f16x8*)(k16 + base + (size_t)(kc + 64 + sr) * 128 + sc8);
            vpre = *(const f16x8*)(v16 + base + (size_t)(kc + 64 + sr) * 128 + sc8);
        }

        // A-operand frags: K rows t*16+lm (kpos), V^T rows dt*16+lm (d)
        f16x8 kf[4];
        #pragma unroll
        for (int t = 0; t < 4; ++t) kf[t] = *(const f16x8*)&Khs[t * 16 + lm][lg * 8];
        f16x8 vf[2][2];
        #pragma unroll
        for (int dt = 0; dt < 2; ++dt)
            #pragma unroll
            for (int ks = 0; ks < 2; ++ks)
                vf[dt][ks] = *(const f16x8*)&Vts[dt * 16 + lm][ks * 32 + lg * 8];

        // ---- two jt-phases: {QK+softmax for 2 tiles -> Pb; PV for 2 tiles} ----
        #pragma unroll
        for (int jh2 = 0; jh2 < 2; ++jh2) {
            #pragma unroll
            for (int t2 = 0; t2 < 2; ++t2) {
                const int jt = jh2 * 2 + t2;
                const float* bj = bias_n + (size_t)h * NPOS
                                + (size_t)(j0w + jt * 16 + lm) * 256 + kc + lg * 4;
                float s[16];
                #pragma unroll
                for (int t = 0; t < 4; ++t) {
                    float4 bv = *(const float4*)(bj + t * 16);
                    f32x4 c  = {bv.x, bv.y, bv.z, bv.w};
                    f32x4 cl = {0.f, 0.f, 0.f, 0.f};
                    c  = __builtin_amdgcn_mfma_f32_16x16x32_f16(kf[t], qh[jt], c,  0, 0, 0);
                    cl = __builtin_amdgcn_mfma_f32_16x16x32_f16(kf[t], ql[jt], cl, 0, 0, 0);
                    #pragma unroll
                    for (int rr = 0; rr < 4; ++rr)
                        s[t * 4 + rr] = c[rr] + cl[rr] * (1.0f / 2048.0f);
                }
                // pairwise max tree (associative -> bit-identical; fuses to v_max3)
                float m01 = fmaxf(fmaxf(s[0],  s[1]),  fmaxf(s[2],  s[3]));
                float m23 = fmaxf(fmaxf(s[4],  s[5]),  fmaxf(s[6],  s[7]));
                float m45 = fmaxf(fmaxf(s[8],  s[9]),  fmaxf(s[10], s[11]));
                float m67 = fmaxf(fmaxf(s[12], s[13]), fmaxf(s[14], s[15]));
                float mx  = fmaxf(fmaxf(m01, m23), fmaxf(m45, m67));
                mx = fmaxf(mx, __shfl_xor(mx, 16));
                mx = fmaxf(mx, __shfl_xor(mx, 32));
                float mn = fmaxf(mrow[jt], mx);
                float alpha = __expf(mrow[jt] - mn);
                mrow[jt] = mn;
                float ps = 0.f;
                #pragma unroll
                for (int e = 0; e < 16; ++e) { s[e] = __expf(s[e] - mn); ps += s[e]; }
                ps += __shfl_xor(ps, 16);
                ps += __shfl_xor(ps, 32);
                lrow[jt] = lrow[jt] * alpha + ps;
                #pragma unroll
                for (int dt = 0; dt < 2; ++dt)
                    #pragma unroll
                    for (int rr = 0; rr < 4; ++rr) Oacc[dt][jt][rr] *= alpha;
                #pragma unroll
                for (int t = 0; t < 4; ++t) {
                    f16x4 pv;
                    #pragma unroll
                    for (int rr = 0; rr < 4; ++rr) pv[rr] = (_Float16)s[t * 4 + rr];
                    *(f16x4*)&Pb[w][t2 * 16 + lm][t * 16 + lg * 4] = pv;
                }
            }

            // ---- O^T += V^T * P^T (per-wave Pb; wave DS in-order, no barrier) ----
            #pragma unroll
            for (int t2 = 0; t2 < 2; ++t2) {
                const int jt = jh2 * 2 + t2;
                f16x8 pf0 = *(const f16x8*)&Pb[w][t2 * 16 + lm][lg * 8];
                f16x8 pf1 = *(const f16x8*)&Pb[w][t2 * 16 + lm][32 + lg * 8];
                #pragma unroll
                for (int dt = 0; dt < 2; ++dt) {
                    f32x4 c = {Oacc[dt][jt][0], Oacc[dt][jt][1], Oacc[dt][jt][2], Oacc[dt][jt][3]};
                    c = __builtin_amdgcn_mfma_f32_16x16x32_f16(vf[dt][0], pf0, c, 0, 0, 0);
                    c = __builtin_amdgcn_mfma_f32_16x16x32_f16(vf[dt][1], pf1, c, 0, 0, 0);
                    Oacc[dt][jt][0] = c[0]; Oacc[dt][jt][1] = c[1];
                    Oacc[dt][jt][2] = c[2]; Oacc[dt][jt][3] = c[3];
                }
            }
        }
    }

    // ---- epilogue: normalize, gate (f16), store go f32 ----
    #pragma unroll
    for (int jt = 0; jt < 4; ++jt) {
        const int j = j0w + jt * 16 + lm;
        const float inv = 1.0f / lrow[jt];
        #pragma unroll
        for (int dt = 0; dt < 2; ++dt) {
            f16x4 gv4 = *(const f16x4*)(g16 + base + (size_t)j * 128 + dt * 16 + lg * 4);
            float4 ov;
            ov.x = Oacc[dt][jt][0] * inv * (float)gv4[0];
            ov.y = Oacc[dt][jt][1] * inv * (float)gv4[1];
            ov.z = Oacc[dt][jt][2] * inv * (float)gv4[2];
            ov.w = Oacc[dt][jt][3] * inv * (float)gv4[3];
            *(float4*)(go + base + (size_t)j * 128 + dt * 16 + lg * 4) = ov;
        }
    }
}

// ---------------------------------------------------------------------------
// Kernel C (round-20): out = go @ Wo + bo as MFMA f16 GEMM, with Bh
// ALIASED onto xh (ln_proj's proven buffer-reuse pattern): after the
// A-fragments are copied to registers, xh is dead, so Bh can reuse it.
// LDS 52.2 -> 34.8KB; with unchanged launch_bounds (256,3) the register
// BUDGET is unchanged (no spill risk), and if actual usage permits 4
// waves/EU, occupancy rises to 4 blocks/CU -> the 256-block tail round
// (1024 blocks @ 3/CU = 768 resident) disappears. Cost: one extra
// barrier on chunk 0 (before overwriting xh).
// ---------------------------------------------------------------------------
__global__ __launch_bounds__(256, 3) void out_proj_kernel(
    const float* __restrict__ go, const _Float16* __restrict__ WoT_hi,
    const float* __restrict__ bo, float* __restrict__ out)
{
    __shared__ _Float16 xh[64][136];
    __shared__ _Float16 xl[64][136];
    _Float16 (*Bh)[136] = xh;          // alias: xh dead after frag copy

    const int tid = threadIdx.x;
    const int p0  = blockIdx.x * 64;
    const int r   = tid >> 2;          // row 0..63
    const int cb  = (tid & 3) * 32;    // col base (4 threads/row)

    // ---- load 32 go values, split hi/lo into LDS ----
    {
        const float4* pr = (const float4*)(go + (size_t)(p0 + r) * 128 + cb);
        #pragma unroll
        for (int i8 = 0; i8 < 4; ++i8) {
            float4 a = pr[i8 * 2], b = pr[i8 * 2 + 1];
            float v[8] = {a.x, a.y, a.z, a.w, b.x, b.y, b.z, b.w};
            f16x8 hv, lv;
            #pragma unroll
            for (int j = 0; j < 8; ++j) {
                _Float16 h = (_Float16)v[j];
                hv[j] = h;
                lv[j] = (_Float16)((v[j] - (float)h) * 2048.0f);
            }
            *(f16x8*)&xh[r][cb + i8 * 8] = hv;
            *(f16x8*)&xl[r][cb + i8 * 8] = lv;
        }
    }
    __syncthreads();

    const int w  = tid >> 6, l = tid & 63;
    const int lm = l & 15, lg = l >> 4;
    const int arow = w * 16 + lm;

    f16x8 ahf[4], alf[4];
    #pragma unroll
    for (int kt = 0; kt < 4; ++kt) {
        ahf[kt] = *(const f16x8*)&xh[arow][kt * 32 + lg * 8];
        alf[kt] = *(const f16x8*)&xl[arow][kt * 32 + lg * 8];
    }

    #pragma unroll
    for (int chunk = 0; chunk < 2; ++chunk) {
        // issue B-chunk global loads (4 x 16B per thread); barrier before
        // overwriting Bh (=xh): chunk 0 -> all frag ds-reads done;
        // chunk 1 -> prior MFMA Bh ds-reads done.
        const _Float16* srch = WoT_hi + (size_t)(chunk * 64) * 128;
        f16x8 breg[4];
        #pragma unroll
        for (int it = 0; it < 4; ++it) {
            int idx = it * 256 + tid;
            breg[it] = *(const f16x8*)(srch + (idx >> 4) * 128 + (idx & 15) * 8);
        }
        __syncthreads();
        #pragma unroll
        for (int it = 0; it < 4; ++it) {
            int idx = it * 256 + tid;
            *(f16x8*)&Bh[idx >> 4][(idx & 15) * 8] = breg[it];
        }
        __syncthreads();

        f32x4 acch[4], accc[4];
        #pragma unroll
        for (int ct = 0; ct < 4; ++ct) {
            acch[ct] = (f32x4){0.f, 0.f, 0.f, 0.f};
            accc[ct] = (f32x4){0.f, 0.f, 0.f, 0.f};
        }
        #pragma unroll
        for (int kt = 0; kt < 4; ++kt) {
            const int koff = kt * 32 + lg * 8;
            #pragma unroll
            for (int ct = 0; ct < 4; ++ct) {
                f16x8 bh = *(const f16x8*)&Bh[ct * 16 + lm][koff];
                acch[ct] = __builtin_amdgcn_mfma_f32_16x16x32_f16(ahf[kt], bh, acch[ct], 0, 0, 0);
                accc[ct] = __builtin_amdgcn_mfma_f32_16x16x32_f16(alf[kt], bh, accc[ct], 0, 0, 0);
            }
        }

        // ---- store: out[p0 + w*16 + lg*4 + rr][chunk*64 + ct*16 + lm] ----
        #pragma unroll
        for (int ct = 0; ct < 4; ++ct) {
            const int col = chunk * 64 + ct * 16 + lm;
            const float bov = bo[col];
            #pragma unroll
            for (int rr = 0; rr < 4; ++rr) {
                const int row = p0 + w * 16 + lg * 4 + rr;
                out[(size_t)row * 128 + col] =
                    acch[ct][rr] + accc[ct][rr] * (1.0f / 2048.0f) + bov;
            }
        }
    }
}

// ---------------------------------------------------------------------------
extern "C" void kernel_launch(void* const* d_in, const int* in_sizes, int n_in,
                              void* d_out, int out_size, void* d_ws, size_t ws_size,
                              hipStream_t stream) {
    const float* pair = (const float*)d_in[0];
    const float* ln_w = (const float*)d_in[1];
    const float* ln_b = (const float*)d_in[2];
    const float* Wq   = (const float*)d_in[3];
    const float* Wk   = (const float*)d_in[4];
    const float* Wv   = (const float*)d_in[5];
    const float* Wb   = (const float*)d_in[6];
    const float* Wg   = (const float*)d_in[7];
    const float* bg   = (const float*)d_in[8];
    const float* Wo   = (const float*)d_in[9];
    const float* bo   = (const float*)d_in[10];

    // workspace: f16 planes q_hi,q_lo,k,v,g (NPOS*128 each) + go f32 + bias_n
    // + WoT_hi (128x128 f16)
    _Float16* q_hi = (_Float16*)d_ws;
    _Float16* q_lo = q_hi + (size_t)NPOS * 128;
    _Float16* k16  = q_lo + (size_t)NPOS * 128;
    _Float16* v16  = k16 + (size_t)NPOS * 128;
    _Float16* g16  = v16 + (size_t)NPOS * 128;
    float* go      = (float*)(g16 + (size_t)NPOS * 128);
    float* bias_n  = go + (size_t)NPOS * 128;
    _Float16* WoT_hi = (_Float16*)(bias_n + 4 * (size_t)NPOS);
    float* out     = (float*)d_out;

    // Transient scratch for transposed hi-plane weights: in d_out
    // (out_proj overwrites all of d_out at the end).
    _Float16* Wt_hi = (_Float16*)d_out;

    hipLaunchKernelGGL(split_w_kernel, dim3(320), dim3(256), 0, stream,
                       Wq, Wk, Wv, Wg, Wo, Wt_hi, WoT_hi);
    hipLaunchKernelGGL(ln_proj_kernel, dim3(1024), dim3(256), 0, stream,
                       pair, ln_w, ln_b, Wb, bg, Wt_hi,
                       q_hi, q_lo, k16, v16, g16, bias_n);
    hipLaunchKernelGGL(attn_kernel, dim3(1024), dim3(256), 0, stream,
                       q_hi, q_lo, k16, v16, g16, bias_n, go);
    hipLaunchKernelGGL(out_proj_kernel, dim3(1024), dim3(256), 0, stream,
                       go, WoT_hi, bo, out);
}